// Round 17
// baseline (1788.343 us; speedup 1.0000x reference)
//
#include <hip/hip_runtime.h>
#include <stdint.h>

// GGNN round 31: degree-sorted gather. r30 datum: conflict-free zero-math
// gload_lds staging left mega at 73us -> mega closed (bound by its serial
// L2/L3 stream; three independent levers all neutral). Last structural
// waste: gather runs each wave for the MAX of its 4 quarters' CSR lengths
// (Poisson(6) -> E[max4]~9.5 vs mean 6 => ~35% masked slots). Fix: one-
// time counting sort by degree (1024 bins, reusing scan1/scan2/finalize),
// gather processes order[i] (16-lane broadcast) and scatters its 768B
// output to the node's real s slot (3x256B spans; writes fire-and-forget,
// gather is read-latency-bound). Mega/s-layout/fill = r27 verbatim;
// embed2 grid-strided (r30-proven). Revert if total>=1041.

typedef _Float16 f16;
typedef _Float16 v8hf __attribute__((ext_vector_type(8)));
typedef _Float16 v2hf __attribute__((ext_vector_type(2)));
typedef float    v16f __attribute__((ext_vector_type(16)));

#define S1F 49152   //  4 tiles * 24 ks * 512 : concat msg_W^T (384K x 128N)
#define S2F 49152   // 12 tiles *  8 ks * 512 : W_ih (128K x 384N)
#define GHF 49152   // 12 tiles *  8 ks * 512 : W_hh
#define NBIN 1024

__device__ __forceinline__ float sigf(float a){
  return __fdividef(1.0f, 1.0f + __expf(-a));
}
__device__ __forceinline__ float tanhf_fast(float a){
  return 1.0f - __fdividef(2.0f, __expf(2.0f*a) + 1.0f);
}

__global__ void k_diag(float* out, int n, float v){
  int i = threadIdx.x; if(i<n) out[i] = v;
}

// grid-strided embed: one v8hf chunk per step (N*16 chunks total).
__global__ void k_embed2(const int* __restrict__ xtype, const int* __restrict__ xtok,
                         const float* __restrict__ xsmall,
                         const float* __restrict__ temb, const float* __restrict__ kemb,
                         f16* __restrict__ xb, int N){
  int total = N*16;
  for(int c = blockIdx.x*blockDim.x + threadIdx.x; c < total; c += gridDim.x*blockDim.x){
    int n = c >> 4, j8 = (c & 15)*8;
    const float* src;
    if(j8 < 32)      src = temb + (size_t)xtype[n]*32 + j8;
    else if(j8 < 64) src = kemb + (size_t)xtok[n]*32 + (j8-32);
    else             src = xsmall + (size_t)n*64 + (j8-64);
    v8hf t;
    #pragma unroll
    for(int k=0;k<8;k++) t[k] = (f16)src[k];
    *(v8hf*)&xb[(size_t)n*128 + j8] = t;
  }
}

// Pack weights f16 in MFMA B-frag order: n = tile*32+(lane&31),
// k = ks*16+(lane>>5)*8+j.
// seg0: B1[n<128][k<384] = msg_W[k/128][n][k%128]   (y = s @ B1^T)
// seg1: B2[n<384][k<128] = W_ih[n][k]
// seg2: B3[n<384][k<128] = W_hh[n][k]
__global__ void k_wprep2(const float* __restrict__ msg_W,
                         const float* __restrict__ W_ih,
                         const float* __restrict__ W_hh,
                         f16* __restrict__ WpF){
  int i = blockIdx.x*256 + threadIdx.x;
  if(i >= S1F + S2F + GHF) return;
  int seg = i / 49152;
  int i2 = i % 49152;
  int grp = i2/512, rem = i2%512;
  int lane = rem/8, j = rem%8;
  float w;
  if(seg == 0){
    int tile = grp/24, ks = grp%24;
    int n = tile*32 + (lane&31);
    int k = ks*16 + (lane>>5)*8 + j;
    w = msg_W[(k>>7)*16384 + n*128 + (k&127)];
  } else {
    int tile = grp/8, ks = grp%8;
    int n = tile*32 + (lane&31);
    int k = ks*16 + (lane>>5)*8 + j;
    const float* W = (seg==1)? W_ih : W_hh;
    w = W[n*128 + k];
  }
  WpF[i] = (f16)w;
}

__global__ void k_hist3(const int* __restrict__ dst, const int* __restrict__ et,
                        int* __restrict__ deg3, int E){
  int e = blockIdx.x*blockDim.x + threadIdx.x;
  if(e<E) atomicAdd(&deg3[dst[e]*3 + et[e]], 1);
}

__global__ void k_scan1(const int* __restrict__ deg, int n, int* __restrict__ part, int* __restrict__ bsum){
  __shared__ int s[256];
  int t = threadIdx.x;
  int base = blockIdx.x*1024 + t*4;
  int v[4]; int sum=0;
  #pragma unroll
  for(int k=0;k<4;k++){ int i=base+k; int d=(i<n)?deg[i]:0; sum+=d; v[k]=sum; }
  s[t]=sum; __syncthreads();
  for(int off=1;off<256;off<<=1){
    int add = (t>=off)? s[t-off] : 0;
    __syncthreads();
    s[t]+=add;
    __syncthreads();
  }
  int excl = (t>0)? s[t-1] : 0;
  #pragma unroll
  for(int k=0;k<4;k++){ int i=base+k; if(i<n) part[i]=v[k]+excl; }
  if(t==255) bsum[blockIdx.x] = s[255];
}

__global__ void k_scan2(const int* __restrict__ bsum, int nb, int* __restrict__ carry){
  if(threadIdx.x==0 && blockIdx.x==0){
    int c=0;
    for(int b=0;b<nb;b++){ carry[b]=c; c+=bsum[b]; }
  }
}

__global__ void k_finalize(const int* __restrict__ part, const int* __restrict__ deg,
                           const int* __restrict__ carry, int n,
                           int* __restrict__ rowptr, int* __restrict__ cursor){
  int i = blockIdx.x*blockDim.x + threadIdx.x;
  if(i>=n) return;
  int incl = part[i] + carry[i>>10];
  rowptr[i+1] = incl;
  cursor[i] = incl - deg[i];
  if(i==0) rowptr[0]=0;
}

// pay stores BYTE offsets of source rows (src*256); max 25.6MB < 2^31.
__global__ void k_fill3(const int* __restrict__ src, const int* __restrict__ dst,
                        const int* __restrict__ et, int* __restrict__ cursor,
                        int* __restrict__ pay, int E){
  int e = blockIdx.x*blockDim.x + threadIdx.x;
  if(e>=E) return;
  int pos = atomicAdd(&cursor[dst[e]*3 + et[e]], 1);
  pay[pos] = src[e] << 8;     // byte offset: 128 f16 * 2B = 256B/row
}

// ---- degree sort (one-time): hist -> scan (reused) -> scatter ----
__global__ void k_deghist(const int* __restrict__ rp3, int* __restrict__ dhist, int N){
  int n = blockIdx.x*blockDim.x + threadIdx.x;
  if(n < N){
    int d = rp3[3*n+3] - rp3[3*n];
    if(d > NBIN-1) d = NBIN-1;
    atomicAdd(&dhist[d], 1);
  }
}
__global__ void k_degscatter(const int* __restrict__ rp3, int* __restrict__ dcur,
                             int* __restrict__ order, int N){
  int n = blockIdx.x*blockDim.x + threadIdx.x;
  if(n < N){
    int d = rp3[3*n+3] - rp3[3*n];
    if(d > NBIN-1) d = NBIN-1;
    int pos = atomicAdd(&dcur[d], 1);
    order[pos] = n;
  }
}

// gather: 4 nodes per wave (one per 16-lane quarter) in DEGREE-SORTED
// order (order[] indirection, 16-lane broadcast). Lane covers 8 f16 cols
// via one v8hf 16B load; f16 packed accumulation; byte-offset pay;
// 3-stream flat split. Output scattered to node n's real s slot
// (3 x 256B contiguous spans).
__global__ void k_gather3_g(const f16* __restrict__ xb, const int* __restrict__ rp3,
                            const int* __restrict__ pay, const int* __restrict__ order,
                            f16* __restrict__ s, int N){
  int tid = threadIdx.x;
  int lane = tid & 63;
  int h = lane >> 4;          // quarter = node select within wave
  int c8b = (lane & 15)*16;   // col byte offset within 256B segment
  const char* xbb = (const char*)xb;
  int oi = blockIdx.x*16 + (tid>>6)*4 + h;
  bool valid = (oi < N);
  int n = valid ? order[oi] : 0;
  int b = n*3;
  int lo = rp3[b], e0 = rp3[b+1], e1 = rp3[b+2], hi = rp3[b+3];
  if(!valid){ lo = 0; e0 = 0; e1 = 0; hi = 0; }
  v8hf a0 = {}, a1 = {}, a2 = {};
  int len = hi - lo;
  int t1 = lo + len/3;
  int t2 = lo + (2*len)/3;
  int iA = lo, iB = t1, iC = t2;
  while(iA < t1 && iB < t2 && iC < hi){
    int pA = pay[iA], pB = pay[iB], pC = pay[iC];
    v8hf uA = *(const v8hf*)(xbb + pA + c8b);
    v8hf uB = *(const v8hf*)(xbb + pB + c8b);
    v8hf uC = *(const v8hf*)(xbb + pC + c8b);
    if(iA < e0)      a0 += uA;
    else if(iA < e1) a1 += uA;
    else             a2 += uA;
    if(iB < e0)      a0 += uB;
    else if(iB < e1) a1 += uB;
    else             a2 += uB;
    if(iC < e0)      a0 += uC;
    else if(iC < e1) a1 += uC;
    else             a2 += uC;
    iA++; iB++; iC++;
  }
  for(; iA < t1; iA++){
    v8hf u = *(const v8hf*)(xbb + pay[iA] + c8b);
    if(iA < e0)      a0 += u;
    else if(iA < e1) a1 += u;
    else             a2 += u;
  }
  for(; iB < t2; iB++){
    v8hf u = *(const v8hf*)(xbb + pay[iB] + c8b);
    if(iB < e0)      a0 += u;
    else if(iB < e1) a1 += u;
    else             a2 += u;
  }
  for(; iC < hi; iC++){
    v8hf u = *(const v8hf*)(xbb + pay[iC] + c8b);
    if(iC < e0)      a0 += u;
    else if(iC < e1) a1 += u;
    else             a2 += u;
  }
  if(valid){
    char* sb = (char*)s + (size_t)n*768 + c8b;
    *(v8hf*)(sb)       = a0;
    *(v8hf*)(sb + 256) = a1;
    *(v8hf*)(sb + 512) = a2;
  }
}

// Two-stage fused GEMM + GRU (r27 verbatim). 32 rows/block, 4 waves;
// wave w = feature slice jf in [32w,32w+32).
// stage1: y = s @ B1^T (K=384, accy) + deg*msg_b, rounded f16 -> Ay (LDS,
//         reusing dead Ss region).
// stage2: r,z gates summed (gh continues in acc0/acc1), gi-n packed,
//         gh-n fresh. Peak acc 48 AGPR -> (256,3).
#define SSTR 392   // 384+8
#define XSTR 136   // 128+8
__global__ __launch_bounds__(256,3) void k_mega2s(
    const f16* __restrict__ xb_old, f16* __restrict__ xb_new,
    const f16* __restrict__ s, const f16* __restrict__ WpF,
    const int* __restrict__ deg3, const float* __restrict__ msg_b,
    const float* __restrict__ b_ih, const float* __restrict__ b_hh, int M)
{
  __shared__ f16 Ss[32*SSTR];   // 24.5 KB; first 32*XSTR reused as Ay
  __shared__ f16 Ax[32*XSTR];   //  8.5 KB
  __shared__ float Dg[96];      // deg3 for this block's 32 rows
  int tid = threadIdx.x, lane = tid & 63, w = tid >> 6;
  int lrow = lane & 31, q = lane >> 5;
  int row0 = blockIdx.x * 32;

  // stage xb rows -> Ax: 512 chunks, 2/thread
  #pragma unroll
  for(int p=0;p<2;p++){
    int ch = tid + p*256;
    int row = ch>>4, c8 = (ch&15)*8;
    int gr = row0 + row; if(gr >= M) gr = M-1;
    *(v8hf*)&Ax[row*XSTR + c8] = *(const v8hf*)(xb_old + (size_t)gr*128 + c8);
  }
  // stage s rows -> Ss: 1536 chunks, 6/thread
  #pragma unroll
  for(int p=0;p<6;p++){
    int ch = tid + p*256;
    int row = ch/48, c8 = (ch%48)*8;
    int gr = row0 + row; if(gr >= M) gr = M-1;
    *(v8hf*)&Ss[row*SSTR + c8] = *(const v8hf*)(s + (size_t)gr*384 + c8);
  }
  // stage deg3 -> Dg
  if(tid < 96){
    int node = row0 + tid/3;
    Dg[tid] = (node < M) ? (float)deg3[node*3 + (tid - (tid/3)*3)] : 0.f;
  }
  __syncthreads();

  int jf = w*32 + lrow;
  int rq4 = 4*q;

  // ---- stage1: y = s @ B1^T over K=384; single 128-wide acc ----
  v16f accy = {};
  #pragma unroll
  for(int ks=0; ks<24; ks++){
    int kb = ks*16 + q*8;
    v8hf a0 = *(const v8hf*)&Ss[lrow*SSTR + kb];
    v8hf by = *(const v8hf*)(WpF + (size_t)(w*24 + ks)*512 + lane*8);
    accy = __builtin_amdgcn_mfma_f32_32x32x16_f16(a0, by, accy, 0,0,0);
  }
  // fold deg*msg_b into y (f32, pre-rounding)
  {
    float m0 = msg_b[jf], m1 = msg_b[128+jf], m2 = msg_b[256+jf];
    #pragma unroll
    for(int r=0;r<16;r++){
      int gl = (r&3) + 8*(r>>2) + rq4;
      accy[r] += Dg[gl*3]*m0 + Dg[gl*3+1]*m1 + Dg[gl*3+2]*m2;
    }
  }
  __syncthreads();   // all waves done reading Ss before Ay overwrites it
  // write y (f16) to Ay in A-operand layout [32][XSTR]
  f16* Ay = Ss;
  #pragma unroll
  for(int r=0;r<16;r++){
    int gl = (r&3) + 8*(r>>2) + rq4;
    Ay[gl*XSTR + jf] = (f16)accy[r];
  }
  __syncthreads();

  // ---- stage2 gi: K=128 over Ay; gates r/z/n -> acc0/acc1/acc2 ----
  v16f acc0 = {}, acc1 = {}, acc2 = {};
  #pragma unroll
  for(int ks=0; ks<8; ks++){
    int kb = ks*16 + q*8;
    v8hf a0 = *(const v8hf*)&Ay[lrow*XSTR + kb];
    v8hf b0 = *(const v8hf*)(WpF + S1F + (size_t)((0*4+w)*8 + ks)*512 + lane*8);
    v8hf b1 = *(const v8hf*)(WpF + S1F + (size_t)((1*4+w)*8 + ks)*512 + lane*8);
    v8hf b2 = *(const v8hf*)(WpF + S1F + (size_t)((2*4+w)*8 + ks)*512 + lane*8);
    acc0 = __builtin_amdgcn_mfma_f32_32x32x16_f16(a0, b0, acc0, 0,0,0);
    acc1 = __builtin_amdgcn_mfma_f32_32x32x16_f16(a0, b1, acc1, 0,0,0);
    acc2 = __builtin_amdgcn_mfma_f32_32x32x16_f16(a0, b2, acc2, 0,0,0);
  }
  // pack ONLY gi-n (8 regs); acc2's AGPRs freed for accn
  v2hf gp2[8];
  #pragma unroll
  for(int rp=0; rp<8; rp++){
    v2hf t; t[0] = (f16)acc2[2*rp]; t[1] = (f16)acc2[2*rp+1];
    gp2[rp] = t;
  }

  // ---- gh: K=128 over Ax; r,z continue into acc0/acc1; n fresh ----
  v16f accn = {};
  #pragma unroll
  for(int ks=0; ks<8; ks++){
    int kb = ks*16 + q*8;
    v8hf a0 = *(const v8hf*)&Ax[lrow*XSTR + kb];
    v8hf b0 = *(const v8hf*)(WpF + S1F + S2F + (size_t)((0*4+w)*8 + ks)*512 + lane*8);
    v8hf b1 = *(const v8hf*)(WpF + S1F + S2F + (size_t)((1*4+w)*8 + ks)*512 + lane*8);
    v8hf b2 = *(const v8hf*)(WpF + S1F + S2F + (size_t)((2*4+w)*8 + ks)*512 + lane*8);
    acc0 = __builtin_amdgcn_mfma_f32_32x32x16_f16(a0, b0, acc0, 0,0,0);
    acc1 = __builtin_amdgcn_mfma_f32_32x32x16_f16(a0, b1, acc1, 0,0,0);
    accn = __builtin_amdgcn_mfma_f32_32x32x16_f16(a0, b2, accn, 0,0,0);
  }

  __syncthreads();   // all waves' gh reads of Ax complete before in-place write

  // GRU epilogue (deg*msg_b already folded into y).
  float br = b_ih[jf]     + b_hh[jf];
  float bz = b_ih[128+jf] + b_hh[128+jf];
  float bi2 = b_ih[256+jf], bh2 = b_hh[256+jf];
  #pragma unroll
  for(int r=0;r<16;r++){
    int gl = (r&3) + 8*(r>>2) + rq4;
    float rg = sigf(acc0[r] + br);
    float zg = sigf(acc1[r] + bz);
    float in_ = (float)gp2[r>>1][r&1] + bi2;
    float hn  = accn[r] + bh2;
    float nn = tanhf_fast(in_ + rg*hn);
    float xo = (float)Ax[gl*XSTR + jf];
    Ax[gl*XSTR + jf] = (f16)((1.f - zg)*nn + zg*xo);   // in-place, own slot
  }
  __syncthreads();
  // coalesced writeback from Ax
  #pragma unroll
  for(int p=0;p<2;p++){
    int ch = tid + p*256;
    int row = ch>>4, c8 = (ch&15)*8;
    int gr = row0 + row;
    if(gr < M)
      *(v8hf*)(xb_new + (size_t)gr*128 + c8) = *(const v8hf*)&Ax[row*XSTR + c8];
  }
}

__device__ __forceinline__ int lb_batch(const int* __restrict__ batch, int N, int g){
  int lo=0, hi=N;
  while(lo<hi){ int mid=(lo+hi)>>1; if(batch[mid]<g) lo=mid+1; else hi=mid; }
  return lo;
}

__global__ void k_pool2(const f16* __restrict__ xb, const int* __restrict__ batch,
                        float* __restrict__ pooled, int N){
  int g = blockIdx.x, slice = blockIdx.y;
  int j = threadIdx.x;
  int lo = lb_batch(batch,N,g), hi = lb_batch(batch,N,g+1);
  float acc = 0.f;
  for(int r=lo+slice; r<hi; r+=32) acc += (float)xb[(size_t)r*128 + j];
  atomicAdd(&pooled[g*128+j], acc);
}

__global__ void k_head(const float* __restrict__ pooled, const int* __restrict__ batch, int N,
                       const float* __restrict__ W1, const float* __restrict__ b1,
                       const float* __restrict__ W2, const float* __restrict__ b2,
                       float* __restrict__ out){
  int g = blockIdx.x; int j = threadIdx.x;
  __shared__ float p[128];
  __shared__ float red[128];
  int lo = lb_batch(batch,N,g), hi = lb_batch(batch,N,g+1);
  float c = (float)(hi-lo); if(c < 1.f) c = 1.f;
  p[j] = pooled[g*128+j] / c;
  __syncthreads();
  float acc = b1[j];
  #pragma unroll 4
  for(int i=0;i<128;i++) acc += W1[j*128+i]*p[i];
  float v = (acc>0.f?acc:0.f) * W2[j];
  red[j] = v; __syncthreads();
  for(int s=64;s>0;s>>=1){ if(j<s) red[j]+=red[j+s]; __syncthreads(); }
  if(j==0) out[g] = red[0] + b2[0];
}

extern "C" void kernel_launch(void* const* d_in, const int* in_sizes, int n_in,
                              void* d_out, int out_size, void* d_ws, size_t ws_size,
                              hipStream_t stream){
  const int*   x_type    = (const int*)d_in[0];
  const int*   x_tok     = (const int*)d_in[1];
  const float* x_small   = (const float*)d_in[2];
  const int*   edge_index= (const int*)d_in[3];
  const int*   edge_type = (const int*)d_in[4];
  const int*   batch     = (const int*)d_in[5];
  const float* type_emb  = (const float*)d_in[6];
  const float* tok_emb   = (const float*)d_in[7];
  const float* msg_W     = (const float*)d_in[8];
  const float* msg_b     = (const float*)d_in[9];
  const float* W_ih      = (const float*)d_in[10];
  const float* W_hh      = (const float*)d_in[11];
  const float* b_ih      = (const float*)d_in[12];
  const float* b_hh      = (const float*)d_in[13];
  const float* pW1       = (const float*)d_in[14];
  const float* pb1       = (const float*)d_in[15];
  const float* pW2       = (const float*)d_in[16];
  const float* pb2       = (const float*)d_in[17];
  float* out = (float*)d_out;

  int N = in_sizes[0];
  int E = in_sizes[3]/2;
  const int* src = edge_index;
  const int* dst = edge_index + E;
  int n3 = 3*N;
  int nch = (n3+1023)/1024;
  int nblk = (N+31)/32;

  char* w = (char*)d_ws;
  size_t off = 0;
  auto alloc = [&](size_t bytes)->char*{ char* p = w + off; off += (bytes + 511) & ~511ull; return p; };
  f16*   xb0    = (f16*)alloc((size_t)N*128*2);       // ping (25.6 MB)
  f16*   xb1    = (f16*)alloc((size_t)N*128*2);       // pong (25.6 MB)
  f16*   s      = (f16*)alloc((size_t)N*384*2);       // gathered sums (76.8 MB)
  int*   deg3   = (int*)alloc((size_t)n3*4);
  int*   part   = (int*)alloc((size_t)n3*4);
  int*   rp3    = (int*)alloc((size_t)(n3+1)*4);
  int*   cursor = (int*)alloc((size_t)n3*4);
  int*   pay    = (int*)alloc((size_t)E*4);
  int*   bsum   = (int*)alloc((size_t)nch*4);
  int*   carry  = (int*)alloc((size_t)nch*4);
  int*   order  = (int*)alloc((size_t)N*4);
  int*   dhist  = (int*)alloc((size_t)NBIN*4);
  int*   dpart  = (int*)alloc((size_t)NBIN*4);
  int*   dcur   = (int*)alloc((size_t)NBIN*4);
  int*   drp    = (int*)alloc((size_t)(NBIN+1)*4);
  int*   dbsum  = (int*)alloc(64*4);
  int*   dcarry = (int*)alloc(64*4);
  f16*   WpF    = (f16*)alloc((size_t)(S1F+S2F+GHF)*2);
  float* pooled = (float*)alloc(64*128*4);
  if(off > ws_size){
    k_diag<<<1,64,0,stream>>>(out, out_size, 1.0e6f + (float)(ws_size>>20));
    return;
  }

  const int tb = 256;
  hipMemsetAsync(deg3, 0, (size_t)n3*4, stream);
  hipMemsetAsync(dhist, 0, (size_t)NBIN*4, stream);
  k_wprep2  <<<(S1F+S2F+GHF+255)/256, 256, 0, stream>>>(msg_W, W_ih, W_hh, WpF);
  k_hist3   <<<(E+tb-1)/tb, tb, 0, stream>>>(dst, edge_type, deg3, E);
  k_scan1   <<<nch, 256, 0, stream>>>(deg3, n3, part, bsum);
  k_scan2   <<<1, 64, 0, stream>>>(bsum, nch, carry);
  k_finalize<<<(n3+tb-1)/tb, tb, 0, stream>>>(part, deg3, carry, n3, rp3, cursor);
  k_fill3   <<<(E+tb-1)/tb, tb, 0, stream>>>(src, dst, edge_type, cursor, pay, E);
  // degree sort (reuses scan kernels on 1024 bins)
  k_deghist <<<(N+tb-1)/tb, tb, 0, stream>>>(rp3, dhist, N);
  k_scan1   <<<1, 256, 0, stream>>>(dhist, NBIN, dpart, dbsum);
  k_scan2   <<<1, 64, 0, stream>>>(dbsum, 1, dcarry);
  k_finalize<<<(NBIN+tb-1)/tb, tb, 0, stream>>>(dpart, dhist, dcarry, NBIN, drp, dcur);
  k_degscatter<<<(N+tb-1)/tb, tb, 0, stream>>>(rp3, dcur, order, N);
  k_embed2  <<<2048, 256, 0, stream>>>(x_type, x_tok, x_small, type_emb, tok_emb, xb0, N);

  f16* xin = xb0;
  f16* xout = xb1;
  for(int it=0; it<8; it++){
    k_gather3_g<<<(N+15)/16, 256, 0, stream>>>(xin, rp3, pay, order, s, N);
    k_mega2s   <<<nblk, 256, 0, stream>>>(xin, xout, s, WpF, deg3, msg_b, b_ih, b_hh, N);
    f16* tmp = xin; xin = xout; xout = tmp;
  }
  // final state is in xin after the swap
  hipMemsetAsync(pooled, 0, 64*128*4, stream);
  k_pool2<<<dim3(64,32), 128, 0, stream>>>(xin, batch, pooled, N);
  k_head <<<64, 128, 0, stream>>>(pooled, batch, N, pW1, pb1, pW2, pb2, out);
}

// Round 18
// 1031.431 us; speedup vs baseline: 1.7338x; 1.7338x over previous
//
#include <hip/hip_runtime.h>
#include <stdint.h>

// GGNN round 32: r27 VERBATIM (session best, 1041.3us) + grid-strided
// embed2 (setup-only). r31 autopsy: degree-sorted gather was a double
// loss - degscatter's 1024-bin atomics serialize (365us), and order[]
// indirection destroyed pay[] read locality (quarters no longer read
// near-contiguous CSR ranges), ~doubling gather. Node-index order IS a
// locality resource; divergence waste was the cheaper evil.
// Converged floors: mega 73us (occupancy/B-traffic/staging all neutral),
// gather 44us (vmem/VALU/table-size all neutral: L3 random-read latency).

typedef _Float16 f16;
typedef _Float16 v8hf __attribute__((ext_vector_type(8)));
typedef _Float16 v2hf __attribute__((ext_vector_type(2)));
typedef float    v16f __attribute__((ext_vector_type(16)));

#define S1F 49152   //  4 tiles * 24 ks * 512 : concat msg_W^T (384K x 128N)
#define S2F 49152   // 12 tiles *  8 ks * 512 : W_ih (128K x 384N)
#define GHF 49152   // 12 tiles *  8 ks * 512 : W_hh

__device__ __forceinline__ float sigf(float a){
  return __fdividef(1.0f, 1.0f + __expf(-a));
}
__device__ __forceinline__ float tanhf_fast(float a){
  return 1.0f - __fdividef(2.0f, __expf(2.0f*a) + 1.0f);
}

__global__ void k_diag(float* out, int n, float v){
  int i = threadIdx.x; if(i<n) out[i] = v;
}

// grid-strided embed: one v8hf chunk per step (N*16 chunks total).
__global__ void k_embed2(const int* __restrict__ xtype, const int* __restrict__ xtok,
                         const float* __restrict__ xsmall,
                         const float* __restrict__ temb, const float* __restrict__ kemb,
                         f16* __restrict__ xb, int N){
  int total = N*16;
  for(int c = blockIdx.x*blockDim.x + threadIdx.x; c < total; c += gridDim.x*blockDim.x){
    int n = c >> 4, j8 = (c & 15)*8;
    const float* src;
    if(j8 < 32)      src = temb + (size_t)xtype[n]*32 + j8;
    else if(j8 < 64) src = kemb + (size_t)xtok[n]*32 + (j8-32);
    else             src = xsmall + (size_t)n*64 + (j8-64);
    v8hf t;
    #pragma unroll
    for(int k=0;k<8;k++) t[k] = (f16)src[k];
    *(v8hf*)&xb[(size_t)n*128 + j8] = t;
  }
}

// Pack weights f16 in MFMA B-frag order: n = tile*32+(lane&31),
// k = ks*16+(lane>>5)*8+j.
// seg0: B1[n<128][k<384] = msg_W[k/128][n][k%128]   (y = s @ B1^T)
// seg1: B2[n<384][k<128] = W_ih[n][k]
// seg2: B3[n<384][k<128] = W_hh[n][k]
__global__ void k_wprep2(const float* __restrict__ msg_W,
                         const float* __restrict__ W_ih,
                         const float* __restrict__ W_hh,
                         f16* __restrict__ WpF){
  int i = blockIdx.x*256 + threadIdx.x;
  if(i >= S1F + S2F + GHF) return;
  int seg = i / 49152;
  int i2 = i % 49152;
  int grp = i2/512, rem = i2%512;
  int lane = rem/8, j = rem%8;
  float w;
  if(seg == 0){
    int tile = grp/24, ks = grp%24;
    int n = tile*32 + (lane&31);
    int k = ks*16 + (lane>>5)*8 + j;
    w = msg_W[(k>>7)*16384 + n*128 + (k&127)];
  } else {
    int tile = grp/8, ks = grp%8;
    int n = tile*32 + (lane&31);
    int k = ks*16 + (lane>>5)*8 + j;
    const float* W = (seg==1)? W_ih : W_hh;
    w = W[n*128 + k];
  }
  WpF[i] = (f16)w;
}

__global__ void k_hist3(const int* __restrict__ dst, const int* __restrict__ et,
                        int* __restrict__ deg3, int E){
  int e = blockIdx.x*blockDim.x + threadIdx.x;
  if(e<E) atomicAdd(&deg3[dst[e]*3 + et[e]], 1);
}

__global__ void k_scan1(const int* __restrict__ deg, int n, int* __restrict__ part, int* __restrict__ bsum){
  __shared__ int s[256];
  int t = threadIdx.x;
  int base = blockIdx.x*1024 + t*4;
  int v[4]; int sum=0;
  #pragma unroll
  for(int k=0;k<4;k++){ int i=base+k; int d=(i<n)?deg[i]:0; sum+=d; v[k]=sum; }
  s[t]=sum; __syncthreads();
  for(int off=1;off<256;off<<=1){
    int add = (t>=off)? s[t-off] : 0;
    __syncthreads();
    s[t]+=add;
    __syncthreads();
  }
  int excl = (t>0)? s[t-1] : 0;
  #pragma unroll
  for(int k=0;k<4;k++){ int i=base+k; if(i<n) part[i]=v[k]+excl; }
  if(t==255) bsum[blockIdx.x] = s[255];
}

__global__ void k_scan2(const int* __restrict__ bsum, int nb, int* __restrict__ carry){
  if(threadIdx.x==0 && blockIdx.x==0){
    int c=0;
    for(int b=0;b<nb;b++){ carry[b]=c; c+=bsum[b]; }
  }
}

__global__ void k_finalize(const int* __restrict__ part, const int* __restrict__ deg,
                           const int* __restrict__ carry, int n,
                           int* __restrict__ rowptr, int* __restrict__ cursor){
  int i = blockIdx.x*blockDim.x + threadIdx.x;
  if(i>=n) return;
  int incl = part[i] + carry[i>>10];
  rowptr[i+1] = incl;
  cursor[i] = incl - deg[i];
  if(i==0) rowptr[0]=0;
}

// pay stores BYTE offsets of source rows (src*256); max 25.6MB < 2^31.
__global__ void k_fill3(const int* __restrict__ src, const int* __restrict__ dst,
                        const int* __restrict__ et, int* __restrict__ cursor,
                        int* __restrict__ pay, int E){
  int e = blockIdx.x*blockDim.x + threadIdx.x;
  if(e>=E) return;
  int pos = atomicAdd(&cursor[dst[e]*3 + et[e]], 1);
  pay[pos] = src[e] << 8;     // byte offset: 128 f16 * 2B = 256B/row
}

// gather: 4 nodes per wave (one per 16-lane quarter), lane covers 8 f16
// cols via one v8hf 16B load. f16 packed accumulation (v_pk_add_f16),
// byte-offset pay -> no mul in address path. At its memory floor.
__global__ void k_gather3_f(const f16* __restrict__ xb, const int* __restrict__ rp3,
                            const int* __restrict__ pay, f16* __restrict__ s, int N){
  int tid = threadIdx.x;
  int lane = tid & 63;
  int h = lane >> 4;          // quarter = node select within wave
  int c8b = (lane & 15)*16;   // col byte offset within row
  const char* xbb = (const char*)xb;
  int n = blockIdx.x*16 + (tid>>6)*4 + h;
  bool valid = (n < N);
  int nn = valid ? n : (N-1);
  int b = nn*3;
  int lo = rp3[b], e0 = rp3[b+1], e1 = rp3[b+2], hi = rp3[b+3];
  if(!valid){ lo = 0; e0 = 0; e1 = 0; hi = 0; }
  v8hf a0 = {}, a1 = {}, a2 = {};
  int len = hi - lo;
  int t1 = lo + len/3;
  int t2 = lo + (2*len)/3;
  int iA = lo, iB = t1, iC = t2;
  while(iA < t1 && iB < t2 && iC < hi){
    int pA = pay[iA], pB = pay[iB], pC = pay[iC];
    v8hf uA = *(const v8hf*)(xbb + pA + c8b);
    v8hf uB = *(const v8hf*)(xbb + pB + c8b);
    v8hf uC = *(const v8hf*)(xbb + pC + c8b);
    if(iA < e0)      a0 += uA;
    else if(iA < e1) a1 += uA;
    else             a2 += uA;
    if(iB < e0)      a0 += uB;
    else if(iB < e1) a1 += uB;
    else             a2 += uB;
    if(iC < e0)      a0 += uC;
    else if(iC < e1) a1 += uC;
    else             a2 += uC;
    iA++; iB++; iC++;
  }
  for(; iA < t1; iA++){
    v8hf u = *(const v8hf*)(xbb + pay[iA] + c8b);
    if(iA < e0)      a0 += u;
    else if(iA < e1) a1 += u;
    else             a2 += u;
  }
  for(; iB < t2; iB++){
    v8hf u = *(const v8hf*)(xbb + pay[iB] + c8b);
    if(iB < e0)      a0 += u;
    else if(iB < e1) a1 += u;
    else             a2 += u;
  }
  for(; iC < hi; iC++){
    v8hf u = *(const v8hf*)(xbb + pay[iC] + c8b);
    if(iC < e0)      a0 += u;
    else if(iC < e1) a1 += u;
    else             a2 += u;
  }
  if(valid){
    char* sb = (char*)s + (size_t)n*768 + c8b;
    *(v8hf*)(sb)       = a0;
    *(v8hf*)(sb + 256) = a1;
    *(v8hf*)(sb + 512) = a2;
  }
}

// Two-stage fused GEMM + GRU. 32 rows/block, 4 waves; wave w = feature
// slice jf in [32w,32w+32).
// stage1: y = s @ B1^T (K=384, accy) + deg*msg_b, rounded f16 -> Ay (LDS,
//         reusing dead Ss region).
// stage2: r,z gates summed (gh continues in acc0/acc1), gi-n packed,
//         gh-n fresh. Peak acc 48 AGPR -> (256,3).
#define SSTR 392   // 384+8
#define XSTR 136   // 128+8
__global__ __launch_bounds__(256,3) void k_mega2s(
    const f16* __restrict__ xb_old, f16* __restrict__ xb_new,
    const f16* __restrict__ s, const f16* __restrict__ WpF,
    const int* __restrict__ deg3, const float* __restrict__ msg_b,
    const float* __restrict__ b_ih, const float* __restrict__ b_hh, int M)
{
  __shared__ f16 Ss[32*SSTR];   // 24.5 KB; first 32*XSTR reused as Ay
  __shared__ f16 Ax[32*XSTR];   //  8.5 KB
  __shared__ float Dg[96];      // deg3 for this block's 32 rows
  int tid = threadIdx.x, lane = tid & 63, w = tid >> 6;
  int lrow = lane & 31, q = lane >> 5;
  int row0 = blockIdx.x * 32;

  // stage xb rows -> Ax: 512 chunks, 2/thread
  #pragma unroll
  for(int p=0;p<2;p++){
    int ch = tid + p*256;
    int row = ch>>4, c8 = (ch&15)*8;
    int gr = row0 + row; if(gr >= M) gr = M-1;
    *(v8hf*)&Ax[row*XSTR + c8] = *(const v8hf*)(xb_old + (size_t)gr*128 + c8);
  }
  // stage s rows -> Ss: 1536 chunks, 6/thread
  #pragma unroll
  for(int p=0;p<6;p++){
    int ch = tid + p*256;
    int row = ch/48, c8 = (ch%48)*8;
    int gr = row0 + row; if(gr >= M) gr = M-1;
    *(v8hf*)&Ss[row*SSTR + c8] = *(const v8hf*)(s + (size_t)gr*384 + c8);
  }
  // stage deg3 -> Dg
  if(tid < 96){
    int node = row0 + tid/3;
    Dg[tid] = (node < M) ? (float)deg3[node*3 + (tid - (tid/3)*3)] : 0.f;
  }
  __syncthreads();

  int jf = w*32 + lrow;
  int rq4 = 4*q;

  // ---- stage1: y = s @ B1^T over K=384; single 128-wide acc ----
  v16f accy = {};
  #pragma unroll
  for(int ks=0; ks<24; ks++){
    int kb = ks*16 + q*8;
    v8hf a0 = *(const v8hf*)&Ss[lrow*SSTR + kb];
    v8hf by = *(const v8hf*)(WpF + (size_t)(w*24 + ks)*512 + lane*8);
    accy = __builtin_amdgcn_mfma_f32_32x32x16_f16(a0, by, accy, 0,0,0);
  }
  // fold deg*msg_b into y (f32, pre-rounding)
  {
    float m0 = msg_b[jf], m1 = msg_b[128+jf], m2 = msg_b[256+jf];
    #pragma unroll
    for(int r=0;r<16;r++){
      int gl = (r&3) + 8*(r>>2) + rq4;
      accy[r] += Dg[gl*3]*m0 + Dg[gl*3+1]*m1 + Dg[gl*3+2]*m2;
    }
  }
  __syncthreads();   // all waves done reading Ss before Ay overwrites it
  // write y (f16) to Ay in A-operand layout [32][XSTR]
  f16* Ay = Ss;
  #pragma unroll
  for(int r=0;r<16;r++){
    int gl = (r&3) + 8*(r>>2) + rq4;
    Ay[gl*XSTR + jf] = (f16)accy[r];
  }
  __syncthreads();

  // ---- stage2 gi: K=128 over Ay; gates r/z/n -> acc0/acc1/acc2 ----
  v16f acc0 = {}, acc1 = {}, acc2 = {};
  #pragma unroll
  for(int ks=0; ks<8; ks++){
    int kb = ks*16 + q*8;
    v8hf a0 = *(const v8hf*)&Ay[lrow*XSTR + kb];
    v8hf b0 = *(const v8hf*)(WpF + S1F + (size_t)((0*4+w)*8 + ks)*512 + lane*8);
    v8hf b1 = *(const v8hf*)(WpF + S1F + (size_t)((1*4+w)*8 + ks)*512 + lane*8);
    v8hf b2 = *(const v8hf*)(WpF + S1F + (size_t)((2*4+w)*8 + ks)*512 + lane*8);
    acc0 = __builtin_amdgcn_mfma_f32_32x32x16_f16(a0, b0, acc0, 0,0,0);
    acc1 = __builtin_amdgcn_mfma_f32_32x32x16_f16(a0, b1, acc1, 0,0,0);
    acc2 = __builtin_amdgcn_mfma_f32_32x32x16_f16(a0, b2, acc2, 0,0,0);
  }
  // pack ONLY gi-n (8 regs); acc2's AGPRs freed for accn
  v2hf gp2[8];
  #pragma unroll
  for(int rp=0; rp<8; rp++){
    v2hf t; t[0] = (f16)acc2[2*rp]; t[1] = (f16)acc2[2*rp+1];
    gp2[rp] = t;
  }

  // ---- gh: K=128 over Ax; r,z continue into acc0/acc1; n fresh ----
  v16f accn = {};
  #pragma unroll
  for(int ks=0; ks<8; ks++){
    int kb = ks*16 + q*8;
    v8hf a0 = *(const v8hf*)&Ax[lrow*XSTR + kb];
    v8hf b0 = *(const v8hf*)(WpF + S1F + S2F + (size_t)((0*4+w)*8 + ks)*512 + lane*8);
    v8hf b1 = *(const v8hf*)(WpF + S1F + S2F + (size_t)((1*4+w)*8 + ks)*512 + lane*8);
    v8hf b2 = *(const v8hf*)(WpF + S1F + S2F + (size_t)((2*4+w)*8 + ks)*512 + lane*8);
    acc0 = __builtin_amdgcn_mfma_f32_32x32x16_f16(a0, b0, acc0, 0,0,0);
    acc1 = __builtin_amdgcn_mfma_f32_32x32x16_f16(a0, b1, acc1, 0,0,0);
    accn = __builtin_amdgcn_mfma_f32_32x32x16_f16(a0, b2, accn, 0,0,0);
  }

  __syncthreads();   // all waves' gh reads of Ax complete before in-place write

  // GRU epilogue (deg*msg_b already folded into y).
  float br = b_ih[jf]     + b_hh[jf];
  float bz = b_ih[128+jf] + b_hh[128+jf];
  float bi2 = b_ih[256+jf], bh2 = b_hh[256+jf];
  #pragma unroll
  for(int r=0;r<16;r++){
    int gl = (r&3) + 8*(r>>2) + rq4;
    float rg = sigf(acc0[r] + br);
    float zg = sigf(acc1[r] + bz);
    float in_ = (float)gp2[r>>1][r&1] + bi2;
    float hn  = accn[r] + bh2;
    float nn = tanhf_fast(in_ + rg*hn);
    float xo = (float)Ax[gl*XSTR + jf];
    Ax[gl*XSTR + jf] = (f16)((1.f - zg)*nn + zg*xo);   // in-place, own slot
  }
  __syncthreads();
  // coalesced writeback from Ax
  #pragma unroll
  for(int p=0;p<2;p++){
    int ch = tid + p*256;
    int row = ch>>4, c8 = (ch&15)*8;
    int gr = row0 + row;
    if(gr < M)
      *(v8hf*)(xb_new + (size_t)gr*128 + c8) = *(const v8hf*)&Ax[row*XSTR + c8];
  }
}

__device__ __forceinline__ int lb_batch(const int* __restrict__ batch, int N, int g){
  int lo=0, hi=N;
  while(lo<hi){ int mid=(lo+hi)>>1; if(batch[mid]<g) lo=mid+1; else hi=mid; }
  return lo;
}

__global__ void k_pool2(const f16* __restrict__ xb, const int* __restrict__ batch,
                        float* __restrict__ pooled, int N){
  int g = blockIdx.x, slice = blockIdx.y;
  int j = threadIdx.x;
  int lo = lb_batch(batch,N,g), hi = lb_batch(batch,N,g+1);
  float acc = 0.f;
  for(int r=lo+slice; r<hi; r+=32) acc += (float)xb[(size_t)r*128 + j];
  atomicAdd(&pooled[g*128+j], acc);
}

__global__ void k_head(const float* __restrict__ pooled, const int* __restrict__ batch, int N,
                       const float* __restrict__ W1, const float* __restrict__ b1,
                       const float* __restrict__ W2, const float* __restrict__ b2,
                       float* __restrict__ out){
  int g = blockIdx.x; int j = threadIdx.x;
  __shared__ float p[128];
  __shared__ float red[128];
  int lo = lb_batch(batch,N,g), hi = lb_batch(batch,N,g+1);
  float c = (float)(hi-lo); if(c < 1.f) c = 1.f;
  p[j] = pooled[g*128+j] / c;
  __syncthreads();
  float acc = b1[j];
  #pragma unroll 4
  for(int i=0;i<128;i++) acc += W1[j*128+i]*p[i];
  float v = (acc>0.f?acc:0.f) * W2[j];
  red[j] = v; __syncthreads();
  for(int s=64;s>0;s>>=1){ if(j<s) red[j]+=red[j+s]; __syncthreads(); }
  if(j==0) out[g] = red[0] + b2[0];
}

extern "C" void kernel_launch(void* const* d_in, const int* in_sizes, int n_in,
                              void* d_out, int out_size, void* d_ws, size_t ws_size,
                              hipStream_t stream){
  const int*   x_type    = (const int*)d_in[0];
  const int*   x_tok     = (const int*)d_in[1];
  const float* x_small   = (const float*)d_in[2];
  const int*   edge_index= (const int*)d_in[3];
  const int*   edge_type = (const int*)d_in[4];
  const int*   batch     = (const int*)d_in[5];
  const float* type_emb  = (const float*)d_in[6];
  const float* tok_emb   = (const float*)d_in[7];
  const float* msg_W     = (const float*)d_in[8];
  const float* msg_b     = (const float*)d_in[9];
  const float* W_ih      = (const float*)d_in[10];
  const float* W_hh      = (const float*)d_in[11];
  const float* b_ih      = (const float*)d_in[12];
  const float* b_hh      = (const float*)d_in[13];
  const float* pW1       = (const float*)d_in[14];
  const float* pb1       = (const float*)d_in[15];
  const float* pW2       = (const float*)d_in[16];
  const float* pb2       = (const float*)d_in[17];
  float* out = (float*)d_out;

  int N = in_sizes[0];
  int E = in_sizes[3]/2;
  const int* src = edge_index;
  const int* dst = edge_index + E;
  int n3 = 3*N;
  int nch = (n3+1023)/1024;
  int nblk = (N+31)/32;

  char* w = (char*)d_ws;
  size_t off = 0;
  auto alloc = [&](size_t bytes)->char*{ char* p = w + off; off += (bytes + 511) & ~511ull; return p; };
  f16*   xb0    = (f16*)alloc((size_t)N*128*2);       // ping (25.6 MB)
  f16*   xb1    = (f16*)alloc((size_t)N*128*2);       // pong (25.6 MB)
  f16*   s      = (f16*)alloc((size_t)N*384*2);       // gathered sums (76.8 MB)
  int*   deg3   = (int*)alloc((size_t)n3*4);
  int*   part   = (int*)alloc((size_t)n3*4);
  int*   rp3    = (int*)alloc((size_t)(n3+1)*4);
  int*   cursor = (int*)alloc((size_t)n3*4);
  int*   pay    = (int*)alloc((size_t)E*4);
  int*   bsum   = (int*)alloc((size_t)nch*4);
  int*   carry  = (int*)alloc((size_t)nch*4);
  f16*   WpF    = (f16*)alloc((size_t)(S1F+S2F+GHF)*2);
  float* pooled = (float*)alloc(64*128*4);
  if(off > ws_size){
    k_diag<<<1,64,0,stream>>>(out, out_size, 1.0e6f + (float)(ws_size>>20));
    return;
  }

  const int tb = 256;
  hipMemsetAsync(deg3, 0, (size_t)n3*4, stream);
  k_wprep2  <<<(S1F+S2F+GHF+255)/256, 256, 0, stream>>>(msg_W, W_ih, W_hh, WpF);
  k_hist3   <<<(E+tb-1)/tb, tb, 0, stream>>>(dst, edge_type, deg3, E);
  k_scan1   <<<nch, 256, 0, stream>>>(deg3, n3, part, bsum);
  k_scan2   <<<1, 64, 0, stream>>>(bsum, nch, carry);
  k_finalize<<<(n3+tb-1)/tb, tb, 0, stream>>>(part, deg3, carry, n3, rp3, cursor);
  k_fill3   <<<(E+tb-1)/tb, tb, 0, stream>>>(src, dst, edge_type, cursor, pay, E);
  k_embed2  <<<2048, 256, 0, stream>>>(x_type, x_tok, x_small, type_emb, tok_emb, xb0, N);

  f16* xin = xb0;
  f16* xout = xb1;
  for(int it=0; it<8; it++){
    k_gather3_f<<<(N+15)/16, 256, 0, stream>>>(xin, rp3, pay, s, N);
    k_mega2s   <<<nblk, 256, 0, stream>>>(xin, xout, s, WpF, deg3, msg_b, b_ih, b_hh, N);
    f16* tmp = xin; xin = xout; xout = tmp;
  }
  // final state is in xin after the swap
  hipMemsetAsync(pooled, 0, 64*128*4, stream);
  k_pool2<<<dim3(64,32), 128, 0, stream>>>(xin, batch, pooled, N);
  k_head <<<64, 128, 0, stream>>>(pooled, batch, N, pW1, pb1, pW2, pb2, out);
}